// Round 13
// baseline (1023.028 us; speedup 1.0000x reference)
//
#include <hip/hip_runtime.h>
#include <hip/hip_fp16.h>
#include <math.h>
#include <stdio.h>

// N=50000, E=800000, IN=128, C=64, H=8, H*C=512
// Round 13 = round 12 + ml allocation fix (was N*16 B for an [N][8] float2
// array = N*64 B -> OOB writes corrupted CSR -> GPU fault). split aliases deg
// (dead after scan_a) to preserve workspace margin (~266.9 MB < 268.4 MB).
// Two-pass src-split attention: per-pass KV half (51MB) fits L3 -> HBM fetch
// should drop from the invariant 822MB. GEMM (r11) unchanged.

using f16x8 = __attribute__((ext_vector_type(8))) _Float16;
using f32x4 = __attribute__((ext_vector_type(4))) float;

__device__ __forceinline__ void load_lds16(const void* g, void* l) {
  __builtin_amdgcn_global_load_lds((const __attribute__((address_space(1))) void*)g,
                                   (__attribute__((address_space(3))) void*)l,
                                   16, 0, 0);
}

// ---------------- CSR build ----------------
__global__ void zero_misc_kernel(int* __restrict__ deg, __half* __restrict__ H,
                                 int N, int Npad) {
  int t = blockIdx.x * 256 + threadIdx.x;
  if (t < N) deg[t] = 0;
  int nz = (Npad - N) * 512 / 8;
  if (t < nz) {
    f16x8 z = {};
    *(f16x8*)(H + (size_t)N * 512 + (size_t)t * 8) = z;
  }
}

__global__ void degree_kernel(const int* __restrict__ dst, int* __restrict__ deg, int E) {
  int e = blockIdx.x * blockDim.x + threadIdx.x;
  if (e < E) atomicAdd(&deg[dst[e]], 1);
}

__global__ __launch_bounds__(256)
void scan_a_kernel(const int* __restrict__ deg, int* __restrict__ rowptr,
                   int* __restrict__ bsum, int n) {
  __shared__ int tmp[256];
  int t = threadIdx.x;
  int i = blockIdx.x * 256 + t;
  int v = (i < n) ? deg[i] : 0;
  tmp[t] = v;
  __syncthreads();
#pragma unroll
  for (int off = 1; off < 256; off <<= 1) {
    int u = (t >= off) ? tmp[t - off] : 0;
    __syncthreads();
    tmp[t] += u;
    __syncthreads();
  }
  if (i < n) rowptr[i + 1] = tmp[t];
  if (t == 255) bsum[blockIdx.x] = tmp[255];
}

__global__ __launch_bounds__(256)
void scan_b_kernel(int* __restrict__ bsum, int nb) {
  __shared__ int tmp[256];
  int t = threadIdx.x;
  int v = (t < nb) ? bsum[t] : 0;
  tmp[t] = v;
  __syncthreads();
#pragma unroll
  for (int off = 1; off < 256; off <<= 1) {
    int u = (t >= off) ? tmp[t - off] : 0;
    __syncthreads();
    tmp[t] += u;
    __syncthreads();
  }
  if (t < nb) bsum[t] = tmp[t] - v;  // exclusive
}

__global__ __launch_bounds__(256)
void scan_c_kernel(int* __restrict__ rowptr, int* __restrict__ cursor,
                   const int* __restrict__ bsum, int n) {
  int i = blockIdx.x * 256 + threadIdx.x;
  if (i < n) {
    int r = rowptr[i + 1] + bsum[blockIdx.x];
    rowptr[i + 1] = r;
    cursor[i + 1] = r;
  }
  if (i == 0) { rowptr[0] = 0; cursor[0] = 0; }
}

__global__ void scatter_kernel(const int* __restrict__ src, const int* __restrict__ dst,
                               int* __restrict__ cursor, int* __restrict__ col, int E) {
  int e = blockIdx.x * blockDim.x + threadIdx.x;
  if (e < E) {
    int pos = atomicAdd(&cursor[dst[e]], 1);
    col[pos] = src[e];
  }
}

// in-place partition of each node's neighbor list: src < NH first; split point out.
__global__ void partition_kernel(const int* __restrict__ rowptr, int* __restrict__ col,
                                 int* __restrict__ split, int N, int NH) {
  int n = blockIdx.x * 256 + threadIdx.x;
  if (n >= N) return;
  int lo = rowptr[n], hi = rowptr[n + 1];
  int i = lo;
  for (int j = lo; j < hi; ++j) {
    int c = col[j];
    if (c < NH) { col[j] = col[i]; col[i] = c; ++i; }
  }
  split[n] = i;
}

// ---------------- prep: weights/biases ----------------
__global__ __launch_bounds__(256)
void transpose_all_kernel(
    const float* __restrict__ Wq0, const float* __restrict__ Wk0,
    const float* __restrict__ Wv0, const float* __restrict__ Ws0,
    const float* __restrict__ Wq1, const float* __restrict__ Wk1,
    const float* __restrict__ Wv1, const float* __restrict__ Ws1,
    const float* __restrict__ Wq2, const float* __restrict__ Wk2,
    const float* __restrict__ Wv2, const float* __restrict__ Ws2,
    __half* __restrict__ Wt) {
  int z = blockIdx.z;
  int layer = z >> 2, m = z & 3;
  int K = (layer == 0) ? 128 : 512;
  int D = (layer == 2) ? 64 : 512;
  int c0 = blockIdx.x * 32, k0 = blockIdx.y * 32;
  if (c0 >= D || k0 >= K) return;
  const float* W;
  switch (z) {
    case 0: W = Wq0; break; case 1: W = Wk0; break;
    case 2: W = Wv0; break; case 3: W = Ws0; break;
    case 4: W = Wq1; break; case 5: W = Wk1; break;
    case 6: W = Wv1; break; case 7: W = Ws1; break;
    case 8: W = Wq2; break; case 9: W = Wk2; break;
    case 10: W = Wv2; break; default: W = Ws2; break;
  }
  __half* dstBase = Wt + ((layer == 0) ? 0 : (layer == 1) ? 262144 : 1310720);
  __shared__ float t[32][33];
  int tx = threadIdx.x & 31, ty = threadIdx.x >> 5;  // (32,8)
#pragma unroll
  for (int r = 0; r < 4; ++r)
    t[ty + 8 * r][tx] = W[(size_t)(k0 + ty + 8 * r) * D + c0 + tx];
  __syncthreads();
#pragma unroll
  for (int r = 0; r < 4; ++r)
    dstBase[(size_t)(m * D + c0 + ty + 8 * r) * K + k0 + tx] =
        __float2half(t[tx][ty + 8 * r]);
}

__global__ void bias_all_kernel(
    const float* __restrict__ b0, const float* __restrict__ b1,
    const float* __restrict__ b2, const float* __restrict__ b3,
    const float* __restrict__ b4, const float* __restrict__ b5,
    const float* __restrict__ b6, const float* __restrict__ b7,
    const float* __restrict__ b8, const float* __restrict__ b9,
    const float* __restrict__ b10, const float* __restrict__ b11,
    float* __restrict__ bias_arena) {
  int z = blockIdx.x;
  int layer = z >> 2, m = z & 3;
  int D = (layer == 2) ? 64 : 512;
  const float* b;
  switch (z) {
    case 0: b = b0; break; case 1: b = b1; break;
    case 2: b = b2; break; case 3: b = b3; break;
    case 4: b = b4; break; case 5: b = b5; break;
    case 6: b = b6; break; case 7: b = b7; break;
    case 8: b = b8; break; case 9: b = b9; break;
    case 10: b = b10; break; default: b = b11; break;
  }
  float* dst = bias_arena + ((layer == 0) ? 0 : (layer == 1) ? 2048 : 4096) + m * D;
  for (int c = threadIdx.x; c < D; c += 256) dst[c] = b[c];
}

// ---------------- MFMA GEMM: 128x256 block tile, 64x128 wave tile (r11) ----------------
template <int LAYER>
__global__ __launch_bounds__(256, 2)
void gemm_mfma_kernel(const void* __restrict__ Avoid,
                      const __half* __restrict__ Wt,
                      const float* __restrict__ bias,
                      __half* __restrict__ QS, __half* __restrict__ KV,
                      int Nrows) {
  constexpr int K = (LAYER == 0) ? 128 : 512;
  constexpr int dshift = (LAYER == 2) ? 6 : 9;
  constexpr int lda = (LAYER == 0) ? 128 : 512;
  constexpr int NT = (LAYER == 2) ? 1 : 8;
  __shared__ __align__(16) __half As[128 * 64];
  __shared__ __align__(16) __half Bs[256 * 64];
  int tid = threadIdx.x;
  int wave = tid >> 6, lane = tid & 63;
  int wr = wave >> 1, wc = wave & 1;
  int bid = blockIdx.x;
  int xcd = bid & 7;
  int r = bid >> 3;
  int n0 = (r % NT) * 256;
  int m0 = ((r / NT) * 8 + xcd) * 128;
  int srow = lane >> 3;
  int sslot = lane & 7;
  int skc = (sslot ^ srow) << 3;
  int quad = lane >> 4, rr = lane & 15;

  f32x4 acc[4][8] = {};

  for (int kt = 0; kt < K; kt += 64) {
#pragma unroll
    for (int p = 0; p < 4; ++p) {
      int rbase = wave * 32 + p * 8;
      if constexpr (LAYER == 0) {
        int row = m0 + rbase + srow;
        const float* ga = (const float*)Avoid + (size_t)row * lda + kt + skc;
        f16x8 hv = {};
        if (row < Nrows) {
          float4 f0 = *(const float4*)ga;
          float4 f1 = *(const float4*)(ga + 4);
          hv[0] = (_Float16)f0.x; hv[1] = (_Float16)f0.y;
          hv[2] = (_Float16)f0.z; hv[3] = (_Float16)f0.w;
          hv[4] = (_Float16)f1.x; hv[5] = (_Float16)f1.y;
          hv[6] = (_Float16)f1.z; hv[7] = (_Float16)f1.w;
        }
        *(f16x8*)&As[(rbase + srow) * 64 + sslot * 8] = hv;
      } else {
        const __half* ga = (const __half*)Avoid +
                           (size_t)(m0 + rbase + srow) * lda + kt + skc;
        load_lds16(ga, &As[rbase * 64]);
      }
    }
#pragma unroll
    for (int p = 0; p < 8; ++p) {
      int rbase = wave * 64 + p * 8;
      const __half* gb = Wt + (size_t)(n0 + rbase + srow) * K + kt + skc;
      load_lds16(gb, &Bs[rbase * 64]);
    }
    __syncthreads();
#pragma unroll
    for (int h = 0; h < 2; ++h) {
      int c = h * 4 + quad;
      f16x8 a[4], b[8];
#pragma unroll
      for (int i = 0; i < 4; ++i) {
        int row = wr * 64 + i * 16 + rr;
        a[i] = *(const f16x8*)&As[row * 64 + ((c ^ (row & 7)) << 3)];
      }
#pragma unroll
      for (int j = 0; j < 8; ++j) {
        int row = wc * 128 + j * 16 + rr;
        b[j] = *(const f16x8*)&Bs[row * 64 + ((c ^ (row & 7)) << 3)];
      }
#pragma unroll
      for (int i = 0; i < 4; ++i)
#pragma unroll
        for (int j = 0; j < 8; ++j)
          acc[i][j] = __builtin_amdgcn_mfma_f32_16x16x32_f16(a[i], b[j], acc[i][j], 0, 0, 0);
    }
    __syncthreads();
  }

  int col = lane & 15, rb = (lane >> 4) * 4;
  constexpr int D = 1 << dshift;
  constexpr int rstride = D << 1;
#pragma unroll
  for (int j = 0; j < 8; ++j) {
    int gc = n0 + wc * 128 + j * 16 + col;
    float bj = bias[gc];
    int mseg = gc >> dshift;
    int off = gc & (D - 1);
    bool toKV = (mseg == 1) || (mseg == 2);
    __half* base = toKV ? (KV + off + (mseg == 2 ? D : 0))
                        : (QS + off + (mseg == 3 ? D : 0));
#pragma unroll
    for (int i = 0; i < 4; ++i) {
#pragma unroll
      for (int rg = 0; rg < 4; ++rg) {
        int gr = m0 + wr * 64 + i * 16 + rb + rg;
        base[(size_t)gr * rstride] = __float2half(acc[i][j][rg] + bj);
      }
    }
  }
}

// ---------------- two-pass attention H=8 C=64: one WAVE per node ----------------
// PASS 1: edges [rowptr[n], split[n]) (src < NH). State out: o fp16 -> Hbuf,
//         (m,l) fp32 -> ml[n*8+head] (float2).
// PASS 2: edges [split[n], rowptr[n+1]); state in; finalize relu(o/l + S) -> Hbuf.
template <int PASS>
__global__ __launch_bounds__(256)
void attn_h8_kernel(const __half* __restrict__ QS, const __half* __restrict__ KV,
                    const int* __restrict__ rowptr, const int* __restrict__ split,
                    const int* __restrict__ col,
                    __half* __restrict__ Hbuf, float* __restrict__ ml, int N) {
  int n = blockIdx.x * 4 + (threadIdx.x >> 6);
  if (n >= N) return;
  int lane = threadIdx.x & 63;
  size_t rbase = (size_t)n * 1024 + lane * 8;
  size_t hbase = (size_t)n * 512 + lane * 8;

  f16x8 qv = __builtin_nontemporal_load((const f16x8*)(QS + rbase));
  float qf[8];
#pragma unroll
  for (int j = 0; j < 8; ++j) qf[j] = (float)qv[j];

  int e0, e1;
  if (PASS == 1) { e0 = rowptr[n]; e1 = split[n]; }
  else           { e0 = split[n];  e1 = rowptr[n + 1]; }

  float m, l;
  float o[8];
  if (PASS == 1) {
    m = -INFINITY; l = 0.f;
#pragma unroll
    for (int c = 0; c < 8; ++c) o[c] = 0.f;
  } else {
    f16x8 ov = *(const f16x8*)(Hbuf + hbase);
#pragma unroll
    for (int c = 0; c < 8; ++c) o[c] = (float)ov[c];
    float2 mlv = ((const float2*)ml)[n * 8 + (lane >> 3)];
    m = mlv.x; l = mlv.y;
  }

  // 2-deep pair pipeline
  f16x8 ka = {}, va = {}, kb = {}, vb = {};
  int i = e0;
  if (i < e1) {
    const __half* p = KV + (size_t)col[i] * 1024 + lane * 8;
    ka = *(const f16x8*)p; va = *(const f16x8*)(p + 512);
  }
  if (i + 1 < e1) {
    const __half* p = KV + (size_t)col[i + 1] * 1024 + lane * 8;
    kb = *(const f16x8*)p; vb = *(const f16x8*)(p + 512);
  }
  while (i < e1) {
    int rem = e1 - i;
    f16x8 kc = {}, vc = {}, kd = {}, vd = {};
    if (rem > 2) {
      const __half* p = KV + (size_t)col[i + 2] * 1024 + lane * 8;
      kc = *(const f16x8*)p; vc = *(const f16x8*)(p + 512);
    }
    if (rem > 3) {
      const __half* p = KV + (size_t)col[i + 3] * 1024 + lane * 8;
      kd = *(const f16x8*)p; vd = *(const f16x8*)(p + 512);
    }
    float pa = 0.f, pb = 0.f;
#pragma unroll
    for (int j = 0; j < 8; ++j) { pa += (float)ka[j] * qf[j]; pb += (float)kb[j] * qf[j]; }
    pa += __shfl_xor(pa, 1, 64); pb += __shfl_xor(pb, 1, 64);
    pa += __shfl_xor(pa, 2, 64); pb += __shfl_xor(pb, 2, 64);
    pa += __shfl_xor(pa, 4, 64); pb += __shfl_xor(pb, 4, 64);
    float a0 = pa * 0.125f;
    if (rem > 1) {
      float a1 = pb * 0.125f;
      float mn = fmaxf(m, fmaxf(a0, a1));
      float sc = __expf(m - mn);
      float ea = __expf(a0 - mn), eb = __expf(a1 - mn);
      l = l * sc + ea + eb;
#pragma unroll
      for (int c = 0; c < 8; ++c)
        o[c] = o[c] * sc + ea * (float)va[c] + eb * (float)vb[c];
      m = mn;
    } else {
      float mn = fmaxf(m, a0);
      float sc = __expf(m - mn);
      float ea = __expf(a0 - mn);
      l = l * sc + ea;
#pragma unroll
      for (int c = 0; c < 8; ++c) o[c] = o[c] * sc + ea * (float)va[c];
      m = mn;
    }
    ka = kc; va = vc; kb = kd; vb = vd;
    i += 2;
  }

  if (PASS == 1) {
    f16x8 ov;
#pragma unroll
    for (int c = 0; c < 8; ++c) ov[c] = (_Float16)o[c];
    *(f16x8*)(Hbuf + hbase) = ov;  // cached: re-read by pass 2 shortly
    if ((lane & 7) == 0) ((float2*)ml)[n * 8 + (lane >> 3)] = make_float2(m, l);
  } else {
    float inv = 1.f / (l + 1e-16f);
    f16x8 sv = __builtin_nontemporal_load((const f16x8*)(QS + rbase + 512));
    f16x8 hv;
#pragma unroll
    for (int c = 0; c < 8; ++c) {
      float rr = o[c] * inv + (float)sv[c];
      hv[c] = (_Float16)fmaxf(rr, 0.f);
    }
    __builtin_nontemporal_store(hv, (f16x8*)(Hbuf + hbase));
  }
}

// ---------------- attention H=1 C=64: single pass (footprint 64MB << L3) ----------------
__global__ __launch_bounds__(256)
void attn_h1_kernel(const __half* __restrict__ QS, const __half* __restrict__ KV,
                    const int* __restrict__ rowptr, const int* __restrict__ col,
                    float* __restrict__ out, int N) {
  int n = (blockIdx.x * 256 + threadIdx.x) >> 3;
  if (n >= N) return;
  int gl = threadIdx.x & 7;
  size_t rbase = (size_t)n * 128 + gl * 8;

  f16x8 qv = __builtin_nontemporal_load((const f16x8*)(QS + rbase));
  float qf[8];
#pragma unroll
  for (int j = 0; j < 8; ++j) qf[j] = (float)qv[j];

  int e0 = rowptr[n], e1 = rowptr[n + 1];
  float m = -INFINITY, l = 0.f;
  float o[8] = {};

  f16x8 ka = {}, va = {}, kb = {}, vb = {};
  int i = e0;
  if (i < e1) {
    const __half* p = KV + (size_t)col[i] * 128 + gl * 8;
    ka = *(const f16x8*)p; va = *(const f16x8*)(p + 64);
  }
  if (i + 1 < e1) {
    const __half* p = KV + (size_t)col[i + 1] * 128 + gl * 8;
    kb = *(const f16x8*)p; vb = *(const f16x8*)(p + 64);
  }
  while (i < e1) {
    int rem = e1 - i;
    f16x8 kc = {}, vc = {}, kd = {}, vd = {};
    if (rem > 2) {
      const __half* p = KV + (size_t)col[i + 2] * 128 + gl * 8;
      kc = *(const f16x8*)p; vc = *(const f16x8*)(p + 64);
    }
    if (rem > 3) {
      const __half* p = KV + (size_t)col[i + 3] * 128 + gl * 8;
      kd = *(const f16x8*)p; vd = *(const f16x8*)(p + 64);
    }
    float pa = 0.f, pb = 0.f;
#pragma unroll
    for (int j = 0; j < 8; ++j) { pa += (float)ka[j] * qf[j]; pb += (float)kb[j] * qf[j]; }
    pa += __shfl_xor(pa, 1, 64); pb += __shfl_xor(pb, 1, 64);
    pa += __shfl_xor(pa, 2, 64); pb += __shfl_xor(pb, 2, 64);
    pa += __shfl_xor(pa, 4, 64); pb += __shfl_xor(pb, 4, 64);
    float a0 = pa * 0.125f;
    if (rem > 1) {
      float a1 = pb * 0.125f;
      float mn = fmaxf(m, fmaxf(a0, a1));
      float sc = __expf(m - mn);
      float ea = __expf(a0 - mn), eb = __expf(a1 - mn);
      l = l * sc + ea + eb;
#pragma unroll
      for (int c = 0; c < 8; ++c)
        o[c] = o[c] * sc + ea * (float)va[c] + eb * (float)vb[c];
      m = mn;
    } else {
      float mn = fmaxf(m, a0);
      float sc = __expf(m - mn);
      float ea = __expf(a0 - mn);
      l = l * sc + ea;
#pragma unroll
      for (int c = 0; c < 8; ++c) o[c] = o[c] * sc + ea * (float)va[c];
      m = mn;
    }
    ka = kc; va = vc; kb = kd; vb = vd;
    i += 2;
  }

  float inv = 1.f / (l + 1e-16f);
  f16x8 sv = __builtin_nontemporal_load((const f16x8*)(QS + rbase + 64));
  f32x4 r0, r1;
#pragma unroll
  for (int c = 0; c < 4; ++c) r0[c] = o[c] * inv + (float)sv[c];
#pragma unroll
  for (int c = 0; c < 4; ++c) r1[c] = o[c + 4] * inv + (float)sv[c + 4];
  float* op = out + (size_t)n * 64 + gl * 8;
  *(f32x4*)op = r0;
  *(f32x4*)(op + 4) = r1;
}

extern "C" void kernel_launch(void* const* d_in, const int* in_sizes, int n_in,
                              void* d_out, int out_size, void* d_ws, size_t ws_size,
                              hipStream_t stream) {
  const float* x = (const float*)d_in[0];
  const int* ei = (const int*)d_in[1];
  const int N = in_sizes[0] / 128;
  const int E = in_sizes[1] / 2;
  const int Npad = ((N + 1023) / 1024) * 1024;  // mtiles % 8 == 0
  const int mtiles = Npad / 128;
  const int NH = N / 2;
  const int* srcp = ei;
  const int* dstp = ei + E;

  const float* Wq0 = (const float*)d_in[2];  const float* bq0 = (const float*)d_in[3];
  const float* Wk0 = (const float*)d_in[4];  const float* bk0 = (const float*)d_in[5];
  const float* Wv0 = (const float*)d_in[6];  const float* bv0 = (const float*)d_in[7];
  const float* Ws0 = (const float*)d_in[8];  const float* bs0 = (const float*)d_in[9];
  const float* Wq1 = (const float*)d_in[10]; const float* bq1 = (const float*)d_in[11];
  const float* Wk1 = (const float*)d_in[12]; const float* bk1 = (const float*)d_in[13];
  const float* Wv1 = (const float*)d_in[14]; const float* bv1 = (const float*)d_in[15];
  const float* Ws1 = (const float*)d_in[16]; const float* bs1 = (const float*)d_in[17];
  const float* Wq2 = (const float*)d_in[18]; const float* bq2 = (const float*)d_in[19];
  const float* Wk2 = (const float*)d_in[20]; const float* bk2 = (const float*)d_in[21];
  const float* Wv2 = (const float*)d_in[22]; const float* bv2 = (const float*)d_in[23];
  const float* Ws2 = (const float*)d_in[24]; const float* bs2 = (const float*)d_in[25];

  // ---- workspace layout (~266.9 MB; guard checks) ----
  char* p = (char*)d_ws;
  __half* QS = (__half*)p;               p += (size_t)Npad * 1024 * 2;
  __half* KV = (__half*)p;               p += (size_t)Npad * 1024 * 2;
  __half* H  = (__half*)p;               p += (size_t)Npad * 512 * 2;
  __half* Wt = (__half*)p;               p += (size_t)1441792 * 2;
  float* bias_arena = (float*)p;         p += 4352 * 4;
  float* ml = (float*)p;                 p += (size_t)N * 64;   // [N][8] float2 = 64 B/node
  int* deg    = (int*)p;                 p += (size_t)N * 4;
  int* rowptr = (int*)p;                 p += (size_t)(N + 1) * 4;
  int* cursor = (int*)p;                 p += (size_t)(N + 1) * 4;
  int* colv   = (int*)p;                 p += (size_t)E * 4;
  int* bsum   = (int*)p;                 p += 256 * 4;
  int* split  = deg;  // deg dead after scan_a; partition runs later
  size_t need = p - (char*)d_ws;
  if (ws_size < need) {
    fprintf(stderr, "kernel_launch: ws_size=%zu < need=%zu — aborting cleanly\n",
            ws_size, need);
    return;
  }

  const int nscan = (N + 255) / 256;

  // ---- prep ----
  transpose_all_kernel<<<dim3(16, 16, 12), 256, 0, stream>>>(
      Wq0, Wk0, Wv0, Ws0, Wq1, Wk1, Wv1, Ws1, Wq2, Wk2, Wv2, Ws2, Wt);
  bias_all_kernel<<<12, 256, 0, stream>>>(
      bq0, bk0, bv0, bs0, bq1, bk1, bv1, bs1, bq2, bk2, bv2, bs2, bias_arena);
  {
    int g1 = (N + 255) / 256;
    int g2 = ((Npad - N) * 512 / 8 + 255) / 256;
    zero_misc_kernel<<<(g1 > g2 ? g1 : g2), 256, 0, stream>>>(deg, H, N, Npad);
  }

  // ---- CSR build + src partition ----
  degree_kernel<<<(E + 255) / 256, 256, 0, stream>>>(dstp, deg, E);
  scan_a_kernel<<<nscan, 256, 0, stream>>>(deg, rowptr, bsum, N);
  scan_b_kernel<<<1, 256, 0, stream>>>(bsum, nscan);
  scan_c_kernel<<<nscan, 256, 0, stream>>>(rowptr, cursor, bsum, N);
  scatter_kernel<<<(E + 255) / 256, 256, 0, stream>>>(srcp, dstp, cursor, colv, E);
  partition_kernel<<<nscan, 256, 0, stream>>>(rowptr, colv, split, N, NH);

  __half* Wt0 = Wt;
  __half* Wt1 = Wt + 262144;
  __half* Wt2 = Wt + 1310720;
  const int ablk = (N + 3) / 4;

  // ---- layer 0 ----
  gemm_mfma_kernel<0><<<mtiles * 8, 256, 0, stream>>>(x, Wt0, bias_arena, QS, KV, N);
  attn_h8_kernel<1><<<ablk, 256, 0, stream>>>(QS, KV, rowptr, split, colv, H, ml, N);
  attn_h8_kernel<2><<<ablk, 256, 0, stream>>>(QS, KV, rowptr, split, colv, H, ml, N);

  // ---- layer 1 ----
  gemm_mfma_kernel<1><<<mtiles * 8, 256, 0, stream>>>(H, Wt1, bias_arena + 2048, QS, KV, Npad);
  attn_h8_kernel<1><<<ablk, 256, 0, stream>>>(QS, KV, rowptr, split, colv, H, ml, N);
  attn_h8_kernel<2><<<ablk, 256, 0, stream>>>(QS, KV, rowptr, split, colv, H, ml, N);

  // ---- layer 2 ----
  gemm_mfma_kernel<2><<<mtiles, 256, 0, stream>>>(H, Wt2, bias_arena + 4096, QS, KV, Npad);
  attn_h1_kernel<<<(N + 31) / 32, 256, 0, stream>>>(QS, KV, rowptr, colv,
                                                    (float*)d_out, N);
}